// Round 3
// baseline (277.449 us; speedup 1.0000x reference)
//
#include <hip/hip_runtime.h>

// BeliefMatchingLoss: pred [8,19,512,512] f32 logits, target [8,512,512] int.
// loss = mean over valid pixels of COEF*KL(Dir(alpha)||Dir(1)) - (psi(a_ans)-psi(a0))
//
// Math: shift-2 recurrence. For y = a+2, p = a(a+1):
//   psi(a)    = psi(y) - (2a+1)/p
//   lnGamma(a)= lnGamma(y) - ln p
// psi(y) = ln y - r/2 - r^2/12 + r^4/120          (r=1/y, err<=6.2e-5 @ y=2)
// lnG(y) = (y-.5)ln y - y + ln(2pi)/2 + r/12 - r^3/360   (err<=2.5e-5 @ y=2)
// Sum_c lnGamma(a_c) = Sum_c lnGamma(y_c) - ln(Prod_c p_c), product in fp64,
// one log at the end via exponent/mantissa split.
//
// Structure: 2 px/thread; ALL 19 channel loads issued up front into a
// statically-indexed register array (full unroll), THEN the compute loop --
// one memory-latency window per wave instead of 10 serialized vmcnt(0) waits
// (R2 was latency-convoy-bound: 46% of SIMD cycles nothing issued).

#define NCLS 19
#define HW (512 * 512)          // 2^18
#define NPIX (8 * HW)           // 2097152
#define IGNORE_IDX 255

#define PC1 0.08333333333f      // 1/12
#define PC2 0.00833333333f      // 1/120
#define GL1 0.08333333333f      // 1/12
#define GL2 0.00277777778f      // 1/360
#define HLN2PI 0.918938533205f  // ln(2*pi)/2
#define LN2F 0.693147180560f

__device__ __forceinline__ float fast_rcp(float x) { return __builtin_amdgcn_rcpf(x); }

struct Acc {
    float a0, s2, slgy, dgans;
    double ppd;
};

// one channel contribution for one pixel (shift-2)
__device__ __forceinline__ void chan(float x, int c, int tc, Acc& A) {
    float a  = __expf(x);
    float a1 = a + 1.f, y = a + 2.f;
    float p  = a * a1;
    float rpy = fast_rcp(p * y);
    float r  = p * rpy;                       // 1/y
    float rp = y * rpy;                       // 1/p
    float q  = __fmaf_rn(2.f, a, 1.f);        // 2a+1
    float ly = __logf(y);
    float r2 = r * r;
    float psiy = __fmaf_rn(-r2, __fmaf_rn(-r2, PC2, PC1), __fmaf_rn(-0.5f, r, ly));
    float psia = __fmaf_rn(-q, rp, psiy);
    A.s2 = __fmaf_rn(a - 1.f, psia, A.s2);
    A.a0 += a;
    float lgy = __fmaf_rn(y - 0.5f, ly, -y) + HLN2PI
                + r * __fmaf_rn(-r2, GL2, GL1);
    A.slgy += lgy;
    A.ppd *= (double)p;
    A.dgans = (c == tc) ? psia : A.dgans;
}

__device__ __forceinline__ float finish(const Acc& A) {
    float a0 = A.a0;
    float a1 = a0 + 1.f, y = a0 + 2.f;
    float p  = a0 * a1;
    float rpy = fast_rcp(p * y);
    float r  = p * rpy, rp = y * rpy;
    float q  = __fmaf_rn(2.f, a0, 1.f);
    float ly = __logf(y);
    float r2 = r * r;
    float psi0 = __fmaf_rn(-r2, __fmaf_rn(-r2, PC2, PC1), __fmaf_rn(-0.5f, r, ly))
                 - q * rp;
    float lg0  = __fmaf_rn(y - 0.5f, ly, -y) + HLN2PI
                 + r * __fmaf_rn(-r2, GL2, GL1) - __logf(p);
    // ln of the fp64 product of p_c: exponent/mantissa split
    int hi = __double2hiint(A.ppd);
    int lo = __double2loint(A.ppd);
    int e  = ((hi >> 20) & 0x7FF) - 1023;
    double mant = __hiloint2double((hi & 0x000FFFFF) | 0x3FF00000, lo);  // [1,2)
    float lnpp = __logf((float)mant) + (float)e * LN2F;

    float ll    = A.dgans - psi0;
    float loss1 = lg0 - (A.slgy - lnpp);
    float loss2 = A.s2 - psi0 * (a0 - (float)NCLS);
    return 0.01f * (loss1 + loss2) - ll;
}

__global__ __launch_bounds__(256) void bml_main(const float* __restrict__ pred,
                                                const int* __restrict__ target,
                                                double* __restrict__ ws) {
    int tid = blockIdx.x * blockDim.x + threadIdx.x;
    int p2  = tid << 1;                // first of 2 pixels
    int b   = p2 >> 18;
    int hw  = p2 & (HW - 1);
    const float2* base = (const float2*)(pred + (size_t)b * NCLS * HW + hw);

    int2 t2 = *(const int2*)(target + p2);
    int tc0 = (t2.x == IGNORE_IDX) ? 0 : t2.x;
    int tc1 = (t2.y == IGNORE_IDX) ? 0 : t2.y;

    // Phase 1: issue ALL channel loads (stays in registers: static indexing).
    float2 xs[NCLS];
    #pragma unroll
    for (int c = 0; c < NCLS; ++c)
        xs[c] = base[c * (HW / 2)];

    // Phase 2: consume in order (vmcnt drains progressively).
    Acc A0 = {0.f, 0.f, 0.f, 0.f, 1.0};
    Acc A1 = {0.f, 0.f, 0.f, 0.f, 1.0};
    #pragma unroll
    for (int c = 0; c < NCLS; ++c) {
        chan(xs[c].x, c, tc0, A0);
        chan(xs[c].y, c, tc1, A1);
    }

    float l0 = finish(A0), l1 = finish(A1);

    float local = 0.f;
    unsigned cnt = 0;
    if (t2.x != IGNORE_IDX) { local += l0; cnt++; }
    if (t2.y != IGNORE_IDX) { local += l1; cnt++; }

    #pragma unroll
    for (int off = 32; off; off >>= 1) {
        local += __shfl_down(local, off);
        cnt   += __shfl_down(cnt, off);
    }
    __shared__ float s_sum[4];
    __shared__ unsigned s_cnt[4];
    int lane = threadIdx.x & 63, wid = threadIdx.x >> 6;
    if (lane == 0) { s_sum[wid] = local; s_cnt[wid] = cnt; }
    __syncthreads();
    if (threadIdx.x == 0) {
        float bs = s_sum[0] + s_sum[1] + s_sum[2] + s_sum[3];
        unsigned bc = s_cnt[0] + s_cnt[1] + s_cnt[2] + s_cnt[3];
        atomicAdd(&ws[0], (double)bs);
        atomicAdd(&ws[1], (double)bc);
    }
}

__global__ void bml_finalize(const double* __restrict__ ws, float* __restrict__ out) {
    if (threadIdx.x == 0 && blockIdx.x == 0)
        out[0] = (float)(ws[0] / ws[1]);
}

extern "C" void kernel_launch(void* const* d_in, const int* in_sizes, int n_in,
                              void* d_out, int out_size, void* d_ws, size_t ws_size,
                              hipStream_t stream) {
    const float* pred = (const float*)d_in[0];
    const int* target = (const int*)d_in[1];
    float* out = (float*)d_out;
    double* ws = (double*)d_ws;

    hipMemsetAsync(d_ws, 0, 2 * sizeof(double), stream);

    const int block = 256;
    const int grid = NPIX / (block * 2);  // 4096 blocks, 2 px/thread
    bml_main<<<grid, block, 0, stream>>>(pred, target, ws);
    bml_finalize<<<1, 64, 0, stream>>>(ws, out);
}

// Round 4
// 244.253 us; speedup vs baseline: 1.1359x; 1.1359x over previous
//
#include <hip/hip_runtime.h>

// BeliefMatchingLoss: pred [8,19,512,512] f32 logits, target [8,512,512] int.
// loss = mean over valid px of COEF*KL(Dir(alpha)||Dir(1)) - (psi(a_ans)-psi(a0))
//
// Math: shift-1 recurrence, y = a+1 = exp(x)+1:
//   psi(a)    = psi(y) - 1/a
//   lnGamma(a)= lnGamma(y) - ln a = lnGamma(y) - x      <- logit IS ln a, free!
// psi(y)  = ln y - r/2 - r^2/12 + r^4/120 - r^6/252      (r=1/y)
// lnG(y)  = (y-.5)ln y - y + ln(2pi)/2 + r/12 - r^3/360 + r^5/1260
// Worst-case series bias (y->1, i.e. very negative logit) ~1.7e-3 on psi,
// ~3e-4 on lnG; final scalar threshold is 0.1 -> 50x margin.
// No fp64 product needed (R2/R3's ln Prod p_c == sum of logits exactly).
//
// Structure (the R3 lesson): compiler optimizes for occupancy and will sink a
// register prefetch queue unless (a) launch_bounds permits the VGPRs and
// (b) a sched_barrier(0) fence pins all 19 loads before the compute phase.
// 4 px/thread, float4 channel loads (1 KB/wave-instr), 19 loads in flight per
// wave -> memory throughput-limited instead of latency-convoy-limited.

#define NCLS 19
#define HW (512 * 512)          // 2^18
#define NPIX (8 * HW)           // 2097152
#define IGNORE_IDX 255

#define PC1 0.08333333333f      // 1/12
#define PC2 0.00833333333f      // 1/120
#define PC3 0.00396825397f      // 1/252
#define GL1 0.08333333333f      // 1/12
#define GL2 0.00277777778f      // 1/360
#define GL3 0.00079365079f      // 1/1260
#define HLN2PI 0.9189385332f    // ln(2*pi)/2
#define SUM_HLN2PI 17.45983213f // NCLS * ln(2*pi)/2

__device__ __forceinline__ float fast_rcp(float x) { return __builtin_amdgcn_rcpf(x); }

struct Acc {
    float a0, s2, slgy, sx, dgans;
};

// one channel contribution for one pixel (shift-1); lgy accumulated WITHOUT
// its HLN2PI term (added once per pixel as SUM_HLN2PI).
__device__ __forceinline__ void chan(float x, int c, int tc, Acc& A) {
    float a   = __expf(x);
    float y   = a + 1.f;
    float rpy = fast_rcp(a * y);
    float r   = a * rpy;                 // 1/y
    float rp  = y * rpy;                 // 1/a
    float ly  = __logf(y);
    float r2  = r * r;
    float T   = __fmaf_rn(-r2, __fmaf_rn(-r2, PC3, PC2), PC1);
    float psiy = __fmaf_rn(-r2, T, __fmaf_rn(-0.5f, r, ly));
    float psia = psiy - rp;
    A.s2 = __fmaf_rn(a - 1.f, psia, A.s2);
    A.a0 += a;
    float G   = __fmaf_rn(-r2, __fmaf_rn(-r2, GL3, GL2), GL1);
    float lgp = __fmaf_rn(y - 0.5f, ly, -y);
    A.slgy = __fmaf_rn(r, G, A.slgy + lgp);
    A.sx += x;
    A.dgans = (c == tc) ? psia : A.dgans;
}

__device__ __forceinline__ float finish(const Acc& A) {
    float a0  = A.a0;
    float y   = a0 + 1.f;
    float rpy = fast_rcp(a0 * y);
    float r   = a0 * rpy;                // 1/y
    float rp  = y * rpy;                 // 1/a0
    float ly  = __logf(y);
    float la  = __logf(a0);
    float r2  = r * r;
    float T   = __fmaf_rn(-r2, __fmaf_rn(-r2, PC3, PC2), PC1);
    float psi0 = __fmaf_rn(-r2, T, __fmaf_rn(-0.5f, r, ly)) - rp;
    float G   = __fmaf_rn(-r2, __fmaf_rn(-r2, GL3, GL2), GL1);
    float lg0 = __fmaf_rn(y - 0.5f, ly, -y) + HLN2PI + r * G - la;

    float sum_lg = A.slgy + SUM_HLN2PI - A.sx;       // sum_c lnGamma(a_c)
    float ll    = A.dgans - psi0;
    float loss1 = lg0 - sum_lg;
    float loss2 = A.s2 - psi0 * (a0 - (float)NCLS);
    return 0.01f * (loss1 + loss2) - ll;
}

__global__ __launch_bounds__(256, 2) void bml_main(const float* __restrict__ pred,
                                                   const int* __restrict__ target,
                                                   double* __restrict__ ws) {
    int tid = blockIdx.x * blockDim.x + threadIdx.x;
    int p4  = tid << 2;                // first of 4 pixels
    int b   = p4 >> 18;
    int hw  = p4 & (HW - 1);
    const float4* base = (const float4*)(pred + (size_t)b * NCLS * HW + hw);

    int4 t4 = *(const int4*)(target + p4);
    int tc0 = (t4.x == IGNORE_IDX) ? 0 : t4.x;
    int tc1 = (t4.y == IGNORE_IDX) ? 0 : t4.y;
    int tc2 = (t4.z == IGNORE_IDX) ? 0 : t4.z;
    int tc3 = (t4.w == IGNORE_IDX) ? 0 : t4.w;

    // Phase 1: ALL 19 channel loads in flight (static indexing -> registers).
    float4 xs[NCLS];
    #pragma unroll
    for (int c = 0; c < NCLS; ++c)
        xs[c] = base[c * (HW / 4)];
    // Hard fence: scheduler may not sink the loads into the compute phase.
    __builtin_amdgcn_sched_barrier(0);

    // Phase 2: consume in order; vmcnt drains progressively.
    Acc A0 = {0.f, 0.f, 0.f, 0.f, 0.f};
    Acc A1 = {0.f, 0.f, 0.f, 0.f, 0.f};
    Acc A2 = {0.f, 0.f, 0.f, 0.f, 0.f};
    Acc A3 = {0.f, 0.f, 0.f, 0.f, 0.f};
    #pragma unroll
    for (int c = 0; c < NCLS; ++c) {
        chan(xs[c].x, c, tc0, A0);
        chan(xs[c].y, c, tc1, A1);
        chan(xs[c].z, c, tc2, A2);
        chan(xs[c].w, c, tc3, A3);
    }

    float l0 = finish(A0), l1 = finish(A1), l2 = finish(A2), l3 = finish(A3);

    float local = 0.f;
    unsigned cnt = 0;
    if (t4.x != IGNORE_IDX) { local += l0; cnt++; }
    if (t4.y != IGNORE_IDX) { local += l1; cnt++; }
    if (t4.z != IGNORE_IDX) { local += l2; cnt++; }
    if (t4.w != IGNORE_IDX) { local += l3; cnt++; }

    #pragma unroll
    for (int off = 32; off; off >>= 1) {
        local += __shfl_down(local, off);
        cnt   += __shfl_down(cnt, off);
    }
    __shared__ float s_sum[4];
    __shared__ unsigned s_cnt[4];
    int lane = threadIdx.x & 63, wid = threadIdx.x >> 6;
    if (lane == 0) { s_sum[wid] = local; s_cnt[wid] = cnt; }
    __syncthreads();
    if (threadIdx.x == 0) {
        float bs = s_sum[0] + s_sum[1] + s_sum[2] + s_sum[3];
        unsigned bc = s_cnt[0] + s_cnt[1] + s_cnt[2] + s_cnt[3];
        atomicAdd(&ws[0], (double)bs);
        atomicAdd(&ws[1], (double)bc);
    }
}

__global__ void bml_finalize(const double* __restrict__ ws, float* __restrict__ out) {
    if (threadIdx.x == 0 && blockIdx.x == 0)
        out[0] = (float)(ws[0] / ws[1]);
}

extern "C" void kernel_launch(void* const* d_in, const int* in_sizes, int n_in,
                              void* d_out, int out_size, void* d_ws, size_t ws_size,
                              hipStream_t stream) {
    const float* pred = (const float*)d_in[0];
    const int* target = (const int*)d_in[1];
    float* out = (float*)d_out;
    double* ws = (double*)d_ws;

    hipMemsetAsync(d_ws, 0, 2 * sizeof(double), stream);

    const int block = 256;
    const int grid = NPIX / (block * 4);  // 2048 blocks, 4 px/thread
    bml_main<<<grid, block, 0, stream>>>(pred, target, ws);
    bml_finalize<<<1, 64, 0, stream>>>(ws, out);
}

// Round 5
// 233.165 us; speedup vs baseline: 1.1899x; 1.0476x over previous
//
#include <hip/hip_runtime.h>

// BeliefMatchingLoss: pred [8,19,512,512] f32 logits, target [8,512,512] int.
// loss = mean over valid px of COEF*KL(Dir(alpha)||Dir(1)) - (psi(a_ans)-psi(a0))
//
// Math: shift-1 recurrence, y = a+1 = exp(x)+1:
//   psi(a)    = psi(y) - 1/a
//   lnGamma(a)= lnGamma(y) - ln a = lnGamma(y) - x      <- logit IS ln a, free
// psi(y)  = ln y - r/2 - r^2/12 + r^4/120 - r^6/252      (r=1/y)
// lnG(y)  = (y-.5)ln y - y + ln(2pi)/2 + r/12 - r^3/360 + r^5/1260
// Worst-case series bias ~1.7e-3 on psi; scalar threshold 0.1 -> 50x margin.
//
// R4 lesson: per-block fp64 atomicAdd to TWO shared addresses = 2048
// serialized device-scope RMWs == invisible 30-60us tail (low VALUBusy, low
// BW, "nothing busy"). R5: blocks store disjoint partials; tiny finalize
// kernel reduces them. No atomics anywhere.
//
// Load structure (R3/R4 lesson): all 19 float4 channel loads issued up front
// into a statically-indexed register array, pinned by sched_barrier(0);
// launch_bounds(256,4) caps at 128 VGPR so the ~76-reg queue fits at
// 4 waves/SIMD.

#define NCLS 19
#define HW (512 * 512)          // 2^18
#define NPIX (8 * HW)           // 2097152
#define NBLK 2048
#define IGNORE_IDX 255

#define PC1 0.08333333333f      // 1/12
#define PC2 0.00833333333f      // 1/120
#define PC3 0.00396825397f      // 1/252
#define GL1 0.08333333333f      // 1/12
#define GL2 0.00277777778f      // 1/360
#define GL3 0.00079365079f      // 1/1260
#define HLN2PI 0.9189385332f    // ln(2*pi)/2
#define SUM_HLN2PI 17.45983213f // NCLS * ln(2*pi)/2

__device__ __forceinline__ float fast_rcp(float x) { return __builtin_amdgcn_rcpf(x); }

struct Acc {
    float a0, s2, slgx, dgans;   // slgx accumulates (lnG(y) - HLN2PI - x)
};

__device__ __forceinline__ void chan(float x, int c, int tc, Acc& A) {
    float a   = __expf(x);
    float y   = a + 1.f;
    float rpy = fast_rcp(a * y);
    float r   = a * rpy;                 // 1/y
    float rp  = y * rpy;                 // 1/a
    float ly  = __logf(y);
    float r2  = r * r;
    float T   = __fmaf_rn(-r2, __fmaf_rn(-r2, PC3, PC2), PC1);
    float psiy = __fmaf_rn(-r2, T, __fmaf_rn(-0.5f, r, ly));
    float psia = psiy - rp;
    A.s2 = __fmaf_rn(a - 1.f, psia, A.s2);
    A.a0 += a;
    float G   = __fmaf_rn(-r2, __fmaf_rn(-r2, GL3, GL2), GL1);
    float lgp = __fmaf_rn(y - 0.5f, ly, -y) - x;
    A.slgx = __fmaf_rn(r, G, A.slgx + lgp);
    A.dgans = (c == tc) ? psia : A.dgans;
}

__device__ __forceinline__ float finish(const Acc& A) {
    float a0  = A.a0;
    float y   = a0 + 1.f;
    float rpy = fast_rcp(a0 * y);
    float r   = a0 * rpy;                // 1/y
    float rp  = y * rpy;                 // 1/a0
    float ly  = __logf(y);
    float la  = __logf(a0);
    float r2  = r * r;
    float T   = __fmaf_rn(-r2, __fmaf_rn(-r2, PC3, PC2), PC1);
    float psi0 = __fmaf_rn(-r2, T, __fmaf_rn(-0.5f, r, ly)) - rp;
    float G   = __fmaf_rn(-r2, __fmaf_rn(-r2, GL3, GL2), GL1);
    float lg0 = __fmaf_rn(y - 0.5f, ly, -y) + HLN2PI + r * G - la;

    float sum_lg = A.slgx + SUM_HLN2PI;              // sum_c lnGamma(a_c)
    float ll    = A.dgans - psi0;
    float loss1 = lg0 - sum_lg;
    float loss2 = A.s2 - psi0 * (a0 - (float)NCLS);
    return 0.01f * (loss1 + loss2) - ll;
}

__global__ __launch_bounds__(256, 4) void bml_main(const float* __restrict__ pred,
                                                   const int* __restrict__ target,
                                                   float* __restrict__ partial) {
    int tid = blockIdx.x * blockDim.x + threadIdx.x;
    int p4  = tid << 2;                // first of 4 pixels
    int b   = p4 >> 18;
    int hw  = p4 & (HW - 1);
    const float4* base = (const float4*)(pred + (size_t)b * NCLS * HW + hw);

    // Phase 1: ALL 19 channel loads in flight (static indexing -> registers).
    float4 xs[NCLS];
    #pragma unroll
    for (int c = 0; c < NCLS; ++c)
        xs[c] = base[c * (HW / 4)];
    int4 t4 = *(const int4*)(target + p4);
    // Hard fence: scheduler may not sink the loads into the compute phase.
    __builtin_amdgcn_sched_barrier(0);

    int tc0 = (t4.x == IGNORE_IDX) ? 0 : t4.x;
    int tc1 = (t4.y == IGNORE_IDX) ? 0 : t4.y;
    int tc2 = (t4.z == IGNORE_IDX) ? 0 : t4.z;
    int tc3 = (t4.w == IGNORE_IDX) ? 0 : t4.w;

    // Phase 2: consume in order; vmcnt drains progressively.
    Acc A0 = {0.f, 0.f, 0.f, 0.f};
    Acc A1 = {0.f, 0.f, 0.f, 0.f};
    Acc A2 = {0.f, 0.f, 0.f, 0.f};
    Acc A3 = {0.f, 0.f, 0.f, 0.f};
    #pragma unroll
    for (int c = 0; c < NCLS; ++c) {
        chan(xs[c].x, c, tc0, A0);
        chan(xs[c].y, c, tc1, A1);
        chan(xs[c].z, c, tc2, A2);
        chan(xs[c].w, c, tc3, A3);
    }

    float l0 = finish(A0), l1 = finish(A1), l2 = finish(A2), l3 = finish(A3);

    float local = 0.f;
    float cnt = 0.f;
    if (t4.x != IGNORE_IDX) { local += l0; cnt += 1.f; }
    if (t4.y != IGNORE_IDX) { local += l1; cnt += 1.f; }
    if (t4.z != IGNORE_IDX) { local += l2; cnt += 1.f; }
    if (t4.w != IGNORE_IDX) { local += l3; cnt += 1.f; }

    #pragma unroll
    for (int off = 32; off; off >>= 1) {
        local += __shfl_down(local, off);
        cnt   += __shfl_down(cnt, off);
    }
    __shared__ float s_sum[4];
    __shared__ float s_cnt[4];
    int lane = threadIdx.x & 63, wid = threadIdx.x >> 6;
    if (lane == 0) { s_sum[wid] = local; s_cnt[wid] = cnt; }
    __syncthreads();
    if (threadIdx.x == 0) {
        // disjoint per-block slots -- no atomics, no contention tail
        partial[blockIdx.x]        = s_sum[0] + s_sum[1] + s_sum[2] + s_sum[3];
        partial[NBLK + blockIdx.x] = s_cnt[0] + s_cnt[1] + s_cnt[2] + s_cnt[3];
    }
}

__global__ __launch_bounds__(256) void bml_finalize(const float* __restrict__ partial,
                                                    float* __restrict__ out) {
    double s = 0.0, n = 0.0;
    for (int i = threadIdx.x; i < NBLK; i += 256) {
        s += (double)partial[i];
        n += (double)partial[NBLK + i];
    }
    #pragma unroll
    for (int off = 32; off; off >>= 1) {
        s += __shfl_down(s, off);
        n += __shfl_down(n, off);
    }
    __shared__ double sh_s[4], sh_n[4];
    int lane = threadIdx.x & 63, wid = threadIdx.x >> 6;
    if (lane == 0) { sh_s[wid] = s; sh_n[wid] = n; }
    __syncthreads();
    if (threadIdx.x == 0) {
        double ts = sh_s[0] + sh_s[1] + sh_s[2] + sh_s[3];
        double tn = sh_n[0] + sh_n[1] + sh_n[2] + sh_n[3];
        out[0] = (float)(ts / tn);
    }
}

extern "C" void kernel_launch(void* const* d_in, const int* in_sizes, int n_in,
                              void* d_out, int out_size, void* d_ws, size_t ws_size,
                              hipStream_t stream) {
    const float* pred = (const float*)d_in[0];
    const int* target = (const int*)d_in[1];
    float* out = (float*)d_out;
    float* partial = (float*)d_ws;   // 2*NBLK floats; every slot written

    const int block = 256;
    bml_main<<<NBLK, block, 0, stream>>>(pred, target, partial);
    bml_finalize<<<1, 256, 0, stream>>>(partial, out);
}